// Round 3
// baseline (475.751 us; speedup 1.0000x reference)
//
#include <hip/hip_runtime.h>
#include <hip/hip_bf16.h>
#include <stdint.h>

// out = x @ W'^T + bias, W' = FWHT(W rows)/sqrt(n)  (H symmetric, folded into W)
// x (4,2048,8192) f32 -> M=8192, K=8192 ; W (2048,8192) -> N=2048 ; out f32.

#define M_TOTAL 8192
#define K_TOTAL 8192
#define N_TOTAL 2048
#define D_IN 8192

typedef __attribute__((ext_vector_type(8))) short short8;
typedef __attribute__((ext_vector_type(4))) float f32x4;

typedef __attribute__((address_space(1))) void void_g;
typedef __attribute__((address_space(3))) void void_l;

__device__ __forceinline__ short f2bf(float f) {
  __hip_bfloat16 h = __float2bfloat16(f);
  return *reinterpret_cast<short*>(&h);
}

// ---------------- kernel 1: x fp32 -> bf16 ----------------
__global__ void cvt_x_kernel(const float* __restrict__ x, short* __restrict__ xb, long n) {
  long stride = (long)gridDim.x * blockDim.x * 8;
  for (long i = ((long)blockIdx.x * blockDim.x + threadIdx.x) * 8; i < n; i += stride) {
    float4 v0 = *(const float4*)(x + i);
    float4 v1 = *(const float4*)(x + i + 4);
    short8 o;
    o[0] = f2bf(v0.x); o[1] = f2bf(v0.y); o[2] = f2bf(v0.z); o[3] = f2bf(v0.w);
    o[4] = f2bf(v1.x); o[5] = f2bf(v1.y); o[6] = f2bf(v1.z); o[7] = f2bf(v1.w);
    *(short8*)(xb + i) = o;
  }
}

// ---------------- kernel 2: W' = FWHT(W rows) / sqrt(n), bf16 ----------------
__global__ void fwht_w_kernel(const float* __restrict__ W, short* __restrict__ Wh) {
  __shared__ float buf[D_IN];
  const int row = blockIdx.x;
  const float* src = W + (long)row * D_IN;
  for (int i = threadIdx.x; i < D_IN / 4; i += blockDim.x)
    ((float4*)buf)[i] = ((const float4*)src)[i];
  for (int h = 1; h < D_IN; h <<= 1) {
    __syncthreads();
    for (int p = threadIdx.x; p < D_IN / 2; p += blockDim.x) {
      int i = ((p & ~(h - 1)) << 1) | (p & (h - 1));
      float a = buf[i], b = buf[i + h];
      buf[i] = a + b;
      buf[i + h] = a - b;
    }
  }
  __syncthreads();
  const float s = 0.011048543456039806f; // 1/sqrt(8192)
  short* dst = Wh + (long)row * D_IN;
  for (int i = threadIdx.x; i < D_IN; i += blockDim.x)
    dst[i] = f2bf(buf[i] * s);
}

// ---------------- kernel 3: 256x256, BK=32, 4-deep pipelined bf16 GEMM ----------
// A [M][K] bf16, B [N][K] bf16 (W'), C [M][N] f32. 512 threads = 8 waves (2M x 4N).
// LDS ring: 4 buffers x (A slot 16KB + B slot 16KB) = 128 KiB.
// Slot layout chunk-major [kb4][row][8] (kb4 = 16B k-chunk) -> conflict-free b128.
// Stage K-tile t+3 during iter t; ONE fused "vmcnt(8); s_barrier" per K-tile:
// demanded loads are 3 iters (~6 phases) old -> latency fully hidden (T3+T4).
#define BM 256
#define BN 256
#define BK 32
#define NKT (K_TOTAL / BK) // 256

#define ASL(B) ((B) << 13)
#define BSL(B) (32768 + ((B) << 13))

// stage one 256x32 slot: 2 x global_load_lds(16B) per thread.
// SRC includes row*K + (tid>>8)*8 shorts; KCOL = tile k offset (shorts).
#define STAGE(SLOTBASE, SRC, KCOL)                                                                \
  __builtin_amdgcn_global_load_lds((void_g*)((SRC) + (KCOL)),                                     \
                                   (void_l*)&lds[(SLOTBASE) + sdst], 16, 0, 0);                   \
  __builtin_amdgcn_global_load_lds((void_g*)((SRC) + (KCOL) + 16),                                \
                                   (void_l*)&lds[(SLOTBASE) + sdst + 4096], 16, 0, 0);

#define LDA4(SLOT, MH)                                                                            \
  _Pragma("unroll") for (int m = 0; m < 4; ++m)                                                   \
      a[m] = *(const short8*)&lds[(SLOT) + aoff + ((MH) * 64 + m * 16) * 8];

#define LDB4(SLOT)                                                                                \
  _Pragma("unroll") for (int n = 0; n < 4; ++n)                                                   \
      bfr[n] = *(const short8*)&lds[(SLOT) + boff + n * 128];

#define MFMA_BLOCK(MH)                                                                            \
  __builtin_amdgcn_s_setprio(1);                                                                  \
  _Pragma("unroll") for (int m = 0; m < 4; ++m) {                                                 \
    _Pragma("unroll") for (int n = 0; n < 4; ++n)                                                 \
        acc[MH][m][n] =                                                                           \
            __builtin_amdgcn_mfma_f32_16x16x32_bf16(a[m], bfr[n], acc[MH][m][n], 0, 0, 0);        \
  }                                                                                               \
  __builtin_amdgcn_s_setprio(0);

#define W8 asm volatile("s_waitcnt vmcnt(8)\ns_barrier" ::: "memory")
#define W4 asm volatile("s_waitcnt vmcnt(4)\ns_barrier" ::: "memory")
#define W0 asm volatile("s_waitcnt vmcnt(0)\ns_barrier" ::: "memory")

// one K-tile: phase0 {LDB+LDA(mh0), stage A(t+3), bar, 16 MFMA, bar}
//             phase1 {LDA(mh1),     stage B(t+3), bar, 16 MFMA, WAITBAR}
#define KTILE(SB, PB, STG, KP, WAITBAR)                                                           \
  {                                                                                               \
    LDB4(BSL(SB) - 32768 + 32768);                                                                \
    LDA4(ASL(SB), 0);                                                                             \
    if (STG) { STAGE(ASL(PB), aS, (KP)); }                                                        \
    __builtin_amdgcn_s_barrier();                                                                 \
    MFMA_BLOCK(0);                                                                                \
    __builtin_amdgcn_s_barrier();                                                                 \
    LDA4(ASL(SB), 1);                                                                             \
    if (STG) { STAGE(BSL(PB), bS, (KP)); }                                                        \
    __builtin_amdgcn_s_barrier();                                                                 \
    MFMA_BLOCK(1);                                                                                \
    WAITBAR;                                                                                      \
  }

__global__ __launch_bounds__(512, 2) void gemm_kernel(const short* __restrict__ A,
                                                      const short* __restrict__ B,
                                                      const float* __restrict__ bias,
                                                      float* __restrict__ C) {
  __shared__ __attribute__((aligned(16))) short lds[65536]; // 128 KiB

  const int tid = threadIdx.x;
  const int l = tid & 63;
  const int w = tid >> 6;
  const int wm = w >> 2;  // 0..1
  const int wn = w & 3;   // 0..3
  const int lr = l & 15;
  const int lq = l >> 4;

  // XCD-aware bijective swizzle (nwg = 256)
  const int bid = blockIdx.x;
  const int swz = (bid & 7) * 32 + (bid >> 3);
  const int bm = swz >> 3;
  const int bn = swz & 7;
  const long tileM = (long)bm * BM;
  const long tileN = (long)bn * BN;

  const int sdst = tid * 8;
  const short* aS = A + (tileM + (tid & 255)) * (long)K_TOTAL + (tid >> 8) * 8;
  const short* bS = B + (tileN + (tid & 255)) * (long)K_TOTAL + (tid >> 8) * 8;

  const int aoff = lq * 2048 + (wm * 128 + lr) * 8;
  const int boff = lq * 2048 + (wn * 64 + lr) * 8;

  f32x4 acc[2][4][4];
#pragma unroll
  for (int mh = 0; mh < 2; ++mh)
#pragma unroll
    for (int m = 0; m < 4; ++m)
#pragma unroll
      for (int n = 0; n < 4; ++n)
        acc[mh][m][n] = (f32x4){0.f, 0.f, 0.f, 0.f};

  // prologue: stage K-tiles 0,1,2 (12 loads); buffer 0 ready after vmcnt(8)
  STAGE(ASL(0), aS, 0);
  STAGE(BSL(0), bS, 0);
  STAGE(ASL(1), aS, 32);
  STAGE(BSL(1), bS, 32);
  STAGE(ASL(2), aS, 64);
  STAGE(BSL(2), bS, 64);
  W8;

  short8 a[4], bfr[4];

  // main loop: t = 0..251, buffers compile-time via 4x unroll
  for (int t4 = 0; t4 < NKT - 4; t4 += 4) {
#pragma unroll
    for (int u = 0; u < 4; ++u) {
      const int kp = (t4 + u + 3) * BK;
      KTILE(u, ((u + 3) & 3), true, kp, W8);
    }
  }
  // tails: t = 252 (stages 255), 253, 254, 255
  KTILE(0, 3, true, 255 * BK, W8);
  KTILE(1, 0, false, 0, W4);
  KTILE(2, 0, false, 0, W0);
  KTILE(3, 0, false, 0, );

  // epilogue: C = acc + bias
  const int rb0 = (int)tileM + wm * 128 + lq * 4;
  const int cb0 = (int)tileN + wn * 64 + lr;
#pragma unroll
  for (int mh = 0; mh < 2; ++mh)
#pragma unroll
    for (int n = 0; n < 4; ++n) {
      float bv = bias[cb0 + n * 16];
#pragma unroll
      for (int m = 0; m < 4; ++m) {
        const int r0 = rb0 + mh * 64 + m * 16;
#pragma unroll
        for (int r = 0; r < 4; ++r)
          C[(long)(r0 + r) * N_TOTAL + cb0 + n * 16] = acc[mh][m][n][r] + bv;
      }
    }
}

extern "C" void kernel_launch(void* const* d_in, const int* in_sizes, int n_in,
                              void* d_out, int out_size, void* d_ws, size_t ws_size,
                              hipStream_t stream) {
  const float* x = (const float*)d_in[0];
  const float* W = (const float*)d_in[1];
  const float* bias = (const float*)d_in[2];
  float* out = (float*)d_out;

  short* xb = (short*)d_ws;                                          // 134 MB
  short* wh = (short*)((char*)d_ws + (size_t)M_TOTAL * K_TOTAL * 2); // 33.5 MB

  cvt_x_kernel<<<2048, 256, 0, stream>>>(x, xb, (long)M_TOTAL * K_TOTAL);
  fwht_w_kernel<<<N_TOTAL, 256, 0, stream>>>(W, wh);

  const int grid = (M_TOTAL / BM) * (N_TOTAL / BN); // 256
  gemm_kernel<<<grid, 512, 0, stream>>>(xb, wh, bias, out);
}